// Round 1
// baseline (1132.708 us; speedup 1.0000x reference)
//
#include <hip/hip_runtime.h>
#include <hip/hip_bf16.h>
#include <stdint.h>

// Problem: lhs [1,16,4096,64] f32, rhs [1,16,64,4096] f32.
// rhs_t = swap(-1,-2) -> [1,16,4096,64]; BFP-quantize both along K=64
// (BLOCK=32, MBITS=8); C[h,m,n] = sum_k lhs_q[h,m,k]*rhs_q[h,n,k], fp32 out.
// BFP values q*2^(e-7), |q|<=128 are EXACT in bf16 -> bf16 MFMA is exact
// per-product; fp32 MFMA accumulate ~= reference fp32 accumulate.

#define BH 16
#define MDIM 4096
#define NDIM 4096
#define KDIM 64

typedef __bf16 bf16x8 __attribute__((ext_vector_type(8)));
typedef float f32x16 __attribute__((ext_vector_type(16)));

// exact floor(log2(maxabs)) via exponent field (exact for normals; the
// denormal-guard region only matters for all-zero blocks which are forced
// to 0 anyway by the maxabs>0 select).
__device__ __forceinline__ float bfp_quant_val(float x, float maxabs) {
  int e = (int)(__float_as_uint(fmaxf(maxabs, 1e-38f)) >> 23) - 127;
  e = e < -119 ? -119 : e;                         // keep step/rstep normal
  float rstep = __int_as_float((134 - e) << 23);   // 2^(7-e), exact
  float step  = __int_as_float((e + 120) << 23);   // 2^(e-7), exact
  float q = rintf(x * rstep);                      // round-half-even == np.round
  q = fminf(127.0f, fmaxf(-128.0f, q));
  return (maxabs > 0.0f) ? q * step : 0.0f;        // exactly bf16-representable
}

__device__ __forceinline__ unsigned short f32_to_bf16_exact(float r) {
  return (unsigned short)(__float_as_uint(r) >> 16);  // r is exact in bf16
}

// One wave per 64-element row; lanes 0-31 / 32-63 are the two BFP blocks.
__global__ __launch_bounds__(256) void quant_lhs_kernel(
    const float* __restrict__ in, unsigned short* __restrict__ out) {
  int tid = threadIdx.x;
  int lane = tid & 63;
  size_t row = (size_t)blockIdx.x * 4 + (tid >> 6);
  size_t idx = row * KDIM + lane;
  float x = in[idx];
  float v = fabsf(x);
#pragma unroll
  for (int off = 1; off < 32; off <<= 1)
    v = fmaxf(v, __shfl_xor(v, off));   // max within the 32-lane half
  out[idx] = f32_to_bf16_exact(bfp_quant_val(x, v));
}

// Fused transpose + quantize: thread owns column n of rhs[h,:,n] (the K axis
// of rhs_t), reads are coalesced across n, writes rhs_q[h][n][k] row-major.
__global__ __launch_bounds__(256) void quant_rhs_kernel(
    const float* __restrict__ in, unsigned short* __restrict__ out) {
  int h = blockIdx.y;
  int n = blockIdx.x * 256 + threadIdx.x;
  const float* src = in + (size_t)h * KDIM * NDIM + n;
  float x[KDIM];
#pragma unroll
  for (int k = 0; k < KDIM; ++k) x[k] = src[(size_t)k * NDIM];
  float ma0 = 0.0f, ma1 = 0.0f;
#pragma unroll
  for (int k = 0; k < 32; ++k) ma0 = fmaxf(ma0, fabsf(x[k]));
#pragma unroll
  for (int k = 32; k < 64; ++k) ma1 = fmaxf(ma1, fabsf(x[k]));
  unsigned short* dst = out + ((size_t)h * NDIM + n) * KDIM;
#pragma unroll
  for (int g = 0; g < 8; ++g) {
    union { unsigned short us[8]; uint4 v; } pk;
#pragma unroll
    for (int i = 0; i < 8; ++i) {
      int k = g * 8 + i;
      pk.us[i] = f32_to_bf16_exact(bfp_quant_val(x[k], (k < 32) ? ma0 : ma1));
    }
    ((uint4*)dst)[g] = pk.v;
  }
}

// 128x128 C tile per 256-thread block; wave w does rows [w*32, w*32+32) x 128
// cols. K=64 -> 4 MFMA k-steps of 16. Fragments loaded straight from global
// (A/B per head = 1MB bf16, L2-resident); no LDS, no barriers.
// Verified layouts (learn_hip m74/m101): A[m=lane&31][k=(lane>>5)*8+j],
// C/D: col=lane&31, row=(reg&3)+8*(reg>>2)+4*(lane>>5).
__global__ __launch_bounds__(256) void gemm_kernel(
    const unsigned short* __restrict__ aq, const unsigned short* __restrict__ bq,
    float* __restrict__ c) {
  const int h = blockIdx.z;
  const int m0 = blockIdx.x * 128;
  const int n0 = blockIdx.y * 128;
  const int wave = threadIdx.x >> 6;
  const int lane = threadIdx.x & 63;
  const int l31 = lane & 31;
  const int kb = (lane >> 5) * 8;
  const int mBase = m0 + wave * 32;

  const unsigned short* arow = aq + ((size_t)(h * MDIM + mBase + l31) * KDIM + kb);
  const unsigned short* brow = bq + ((size_t)(h * NDIM + n0 + l31) * KDIM + kb);

  f32x16 acc[4] = {};

#pragma unroll
  for (int s = 0; s < 4; ++s) {
    uint4 au = *(const uint4*)(arow + s * 16);
    bf16x8 af = __builtin_bit_cast(bf16x8, au);
#pragma unroll
    for (int j = 0; j < 4; ++j) {
      uint4 bu = *(const uint4*)(brow + (size_t)j * 32 * KDIM + s * 16);
      bf16x8 bfr = __builtin_bit_cast(bf16x8, bu);
      acc[j] = __builtin_amdgcn_mfma_f32_32x32x16_bf16(af, bfr, acc[j], 0, 0, 0);
    }
  }

  float* cbase = c + (size_t)h * MDIM * NDIM;
#pragma unroll
  for (int j = 0; j < 4; ++j) {
    int n = n0 + j * 32 + l31;
#pragma unroll
    for (int r = 0; r < 16; ++r) {
      int row = (r & 3) + 8 * (r >> 2) + 4 * (lane >> 5);
      cbase[(size_t)(mBase + row) * NDIM + n] = acc[j][r];
    }
  }
}

extern "C" void kernel_launch(void* const* d_in, const int* in_sizes, int n_in,
                              void* d_out, int out_size, void* d_ws, size_t ws_size,
                              hipStream_t stream) {
  const float* lhs = (const float*)d_in[0];
  const float* rhs = (const float*)d_in[1];
  float* out = (float*)d_out;

  unsigned short* aq = (unsigned short*)d_ws;                 // 8 MB
  unsigned short* bq = aq + (size_t)BH * MDIM * KDIM;         // +8 MB

  quant_lhs_kernel<<<dim3(BH * MDIM / 4), 256, 0, stream>>>(lhs, aq);
  quant_rhs_kernel<<<dim3(NDIM / 256, BH), 256, 0, stream>>>(rhs, bq);
  gemm_kernel<<<dim3(MDIM / 128, NDIM / 128, BH), 256, 0, stream>>>(aq, bq, out);
}